// Round 3
// baseline (180.636 us; speedup 1.0000x reference)
//
#include <hip/hip_runtime.h>

#define SCALE 0.17677669529663687f  // 1/sqrt(32)

// ---------------------------------------------------------------------------
// Kernel A: per-row projections. 512 blocks x 256 thr, 1 row/block.
// q_ws (fp32, pre-scaled, [i][nd]), kT_ws (fp32, [nd][j]), v_ws (fp32, [j][nd]),
// qW_ws (fp32, [i][c*8+n]) where qW = sum_d q_scaled[i][n*32+d]*We[c][n*32+d]
// ---------------------------------------------------------------------------
__global__ __launch_bounds__(256) void proj_kernel(
    const float* __restrict__ x, const float* __restrict__ Wq,
    const float* __restrict__ Wk, const float* __restrict__ Wv,
    const float* __restrict__ We,
    float* __restrict__ q_ws, float* __restrict__ qW_ws,
    float* __restrict__ kT_ws, float* __restrict__ v_ws) {
  const int t = threadIdx.x;
  const int i = blockIdx.x;
  __shared__ float s_x[64];
  __shared__ float s_q[256];
  if (t < 64) s_x[t] = x[i * 64 + t];
  __syncthreads();
  float aq = 0, ak = 0, av = 0;
#pragma unroll 8
  for (int c = 0; c < 64; ++c) {
    float xc = s_x[c];
    aq += xc * Wq[c * 256 + t];
    ak += xc * Wk[c * 256 + t];
    av += xc * Wv[c * 256 + t];
  }
  q_ws[i * 256 + t] = aq * SCALE;
  s_q[t] = aq * SCALE;
  kT_ws[t * 512 + i] = ak;
  v_ws[i * 256 + t] = av;
  __syncthreads();
#pragma unroll
  for (int u = 0; u < 2; ++u) {
    int rem = t + u * 256;         // c*8+n, 0..511
    int c = rem >> 3, n = rem & 7;
    float a = 0;
#pragma unroll 8
    for (int d = 0; d < 32; ++d) a += s_q[n * 32 + d] * We[c * 256 + n * 32 + d];
    qW_ws[i * 512 + rem] = a;
  }
}

// ---------------------------------------------------------------------------
// Kernel B: fused attention, one block per query row i. 512 blocks x 512 thr.
// logit[n][j] = sum_d q_s[i,n,d]*k[j,n,d] + sum_c e[i,j,c]*qW[i,c*8+n]
// out[i] = (sum_j p*v[j]  +  (sum_j p*e[i,j,:]) @ We) @ Wo + bo
// ---------------------------------------------------------------------------
__global__ __launch_bounds__(512, 4) void attn_kernel(
    const float* __restrict__ e, const float* __restrict__ q_ws,
    const float* __restrict__ qW_ws, const float* __restrict__ kT_ws,
    const float* __restrict__ v_ws,
    const float* __restrict__ We, const float* __restrict__ Wo,
    const float* __restrict__ bo, float* __restrict__ out) {
  const int t = threadIdx.x;
  const int i = blockIdx.x;
  __shared__ __align__(16) float s_p[8 * 512];   // 16 KB, [n][j] probs
  __shared__ float s_aeP[2][512];                // phase-3 partials (jc, n*64+c)
  __shared__ float s_embP[2][256];               // phase-3 partials (jc, nd)
  __shared__ float s_ae[512];
  __shared__ float s_emb[256];

  const float* qrow = q_ws + i * 256;    // block-uniform -> scalar loads
  const float* qwr  = qW_ws + i * 512;   // block-uniform -> scalar loads

  // ---- Phase 1: logits, one j per thread
  {
    const int j = t;
    float acc[8];
#pragma unroll
    for (int h = 0; h < 8; ++h) acc[h] = 0.f;
    // Q.K^T term: coalesced L2 reads of kT[nd][j], uniform q
#pragma unroll
    for (int h = 0; h < 8; ++h) {
#pragma unroll 8
      for (int d = 0; d < 32; ++d) {
        int nd = h * 32 + d;
        acc[h] += kT_ws[nd * 512 + j] * qrow[nd];
      }
    }
    // edge term
    const float4* erow = (const float4*)(e + (size_t)(i * 512 + j) * 64);
#pragma unroll
    for (int c4 = 0; c4 < 16; ++c4) {
      float4 E = erow[c4];
      float ev[4] = {E.x, E.y, E.z, E.w};
#pragma unroll
      for (int cc = 0; cc < 4; ++cc) {
        const float* qwc = qwr + (c4 * 4 + cc) * 8;
#pragma unroll
        for (int h = 0; h < 8; ++h) acc[h] += ev[cc] * qwc[h];
      }
    }
#pragma unroll
    for (int h = 0; h < 8; ++h) s_p[h * 512 + j] = acc[h];
  }
  __syncthreads();

  // ---- Phase 2: softmax per head, 64 lanes per head
  {
    const int n = t >> 6, l64 = t & 63;
    float m = -1e30f;
#pragma unroll
    for (int u = 0; u < 8; ++u) m = fmaxf(m, s_p[n * 512 + l64 + u * 64]);
#pragma unroll
    for (int off = 32; off; off >>= 1) m = fmaxf(m, __shfl_xor(m, off, 64));
    float sum = 0;
#pragma unroll
    for (int u = 0; u < 8; ++u) {
      float p = __expf(s_p[n * 512 + l64 + u * 64] - m);
      s_p[n * 512 + l64 + u * 64] = p;
      sum += p;
    }
#pragma unroll
    for (int off = 32; off; off >>= 1) sum += __shfl_xor(sum, off, 64);
    float inv = 1.0f / sum;
#pragma unroll
    for (int u = 0; u < 8; ++u) s_p[n * 512 + l64 + u * 64] *= inv;
  }
  __syncthreads();

  // ---- Phase 3: weighted sums, j split across 2 chunks
  {
    const int jc = t >> 8, n = (t >> 5) & 7, lane = t & 31;
    float accV = 0, accE0 = 0, accE1 = 0;
    const float* ebase = e + (size_t)(i * 512) * 64 + 2 * lane;
    const float* vbase = v_ws + n * 32 + lane;
    const int j0 = jc * 256;
    for (int j4 = j0; j4 < j0 + 256; j4 += 4) {
      float4 pv = *(const float4*)&s_p[n * 512 + j4];
      float pa[4] = {pv.x, pv.y, pv.z, pv.w};
#pragma unroll
      for (int k = 0; k < 4; ++k) {
        int j = j4 + k;
        float2 ee2 = *(const float2*)(ebase + (size_t)j * 64);
        accE0 += pa[k] * ee2.x;
        accE1 += pa[k] * ee2.y;
        accV += pa[k] * vbase[j * 256];
      }
    }
    s_aeP[jc][n * 64 + 2 * lane] = accE0;
    s_aeP[jc][n * 64 + 2 * lane + 1] = accE1;
    s_embP[jc][n * 32 + lane] = accV;
  }
  __syncthreads();

  // reduce partials
  s_ae[t] = s_aeP[0][t] + s_aeP[1][t];
  __syncthreads();

  // ---- Epilogue: emb[nd] = accV + sum_c ae[n,c]*We[c,nd]
  if (t < 256) {
    float emb = s_embP[0][t] + s_embP[1][t];
    const int n = t >> 5;
#pragma unroll 8
    for (int c = 0; c < 64; ++c) emb += s_ae[n * 64 + c] * We[c * 256 + t];
    s_emb[t] = emb;
  }
  __syncthreads();
  if (t < 64) {
    float o = bo[t];
#pragma unroll 8
    for (int m2 = 0; m2 < 256; ++m2) o += s_emb[m2] * Wo[m2 * 64 + t];
    out[i * 64 + t] = o;
  }
}

extern "C" void kernel_launch(void* const* d_in, const int* in_sizes, int n_in,
                              void* d_out, int out_size, void* d_ws, size_t ws_size,
                              hipStream_t stream) {
  const float* x  = (const float*)d_in[0];
  const float* e  = (const float*)d_in[1];
  const float* Wq = (const float*)d_in[2];
  const float* Wk = (const float*)d_in[3];
  const float* Wv = (const float*)d_in[4];
  const float* We = (const float*)d_in[5];
  const float* Wo = (const float*)d_in[6];
  const float* bo = (const float*)d_in[7];
  float* out = (float*)d_out;

  // workspace layout (fp32)
  float* q_ws  = (float*)d_ws;                 // 131072 f (512x256, scaled)
  float* qW_ws = q_ws + 131072;                // 262144 f (512 x [c*8+n])
  float* kT_ws = qW_ws + 262144;               // 131072 f (256 x 512)
  float* v_ws  = kT_ws + 131072;               // 131072 f (512 x 256)

  hipLaunchKernelGGL(proj_kernel, dim3(512), dim3(256), 0, stream,
                     x, Wq, Wk, Wv, We, q_ws, qW_ws, kT_ws, v_ws);
  hipLaunchKernelGGL(attn_kernel, dim3(512), dim3(512), 0, stream,
                     e, q_ws, qW_ws, kT_ws, v_ws, We, Wo, bo, out);
}

// Round 4
// 162.610 us; speedup vs baseline: 1.1109x; 1.1109x over previous
//
#include <hip/hip_runtime.h>

#define SCALE 0.17677669529663687f  // 1/sqrt(32)

// ---------------------------------------------------------------------------
// Kernel 1: per-row coefficient tables. grid 512 x 256 thr.
// qc_ws[i][c*16+h]:  h<8 : e-coef  = sum_d q_s[i,h,d]*We[c, h*32+d]
//                    h>=8: x-coef  = sum_d q_s[i,h-8,d]*Wk[c, (h-8)*32+d]
// where q_s = (x[i]@Wq)*SCALE.
// ---------------------------------------------------------------------------
__global__ __launch_bounds__(256) void coef_kernel(
    const float* __restrict__ x, const float* __restrict__ Wq,
    const float* __restrict__ Wk, const float* __restrict__ We,
    float* __restrict__ qc_ws) {
  const int t = threadIdx.x, i = blockIdx.x;
  __shared__ float s_x[64], s_q[256];
  if (t < 64) s_x[t] = x[i * 64 + t];
  __syncthreads();
  float a = 0;
#pragma unroll 8
  for (int c = 0; c < 64; ++c) a += s_x[c] * Wq[c * 256 + t];
  s_q[t] = a * SCALE;
  __syncthreads();
  const int c = t >> 2, hb = (t & 3) * 4;   // 4 coefs per thread, contiguous
  const float* W = (hb < 8) ? We : Wk;      // thread-uniform
  float o4[4];
#pragma unroll
  for (int u = 0; u < 4; ++u) {
    int n = (hb + u) & 7;
    const float* wrow = W + c * 256 + n * 32;
    const float* qrow = s_q + n * 32;
    float s = 0;
#pragma unroll
    for (int d = 0; d < 32; ++d) s += qrow[d] * wrow[d];
    o4[u] = s;
  }
#pragma unroll
  for (int u = 0; u < 4; ++u) qc_ws[i * 1024 + t * 4 + u] = o4[u];
}

// ---------------------------------------------------------------------------
// Kernel 2: fused attention, one block per query row. 512 blocks x 512 thr.
// logit[n][j] = sum_c e[i,j,c]*qce[c,n] + sum_c x[j,c]*qcx[c,n]
// out[i] = ((P@X)@Wv + (P@E_i)@We) @ Wo + bo     (head-block-diagonal Wv/We use)
// Lane mapping: c4 = t&15 owns 4 c's (coalesced float4), strip = t>>4 owns 16 j.
// ---------------------------------------------------------------------------
__global__ __launch_bounds__(512, 4) void attn_kernel(
    const float* __restrict__ e, const float* __restrict__ x,
    const float* __restrict__ qc_ws,
    const float* __restrict__ We, const float* __restrict__ Wv,
    const float* __restrict__ Wo, const float* __restrict__ bo,
    float* __restrict__ out) {
  const int t = threadIdx.x, i = blockIdx.x;
  __shared__ __align__(16) float s_qc[1024];      //  4 KB
  __shared__ __align__(16) float s_p[8 * 512];    // 16 KB
  __shared__ __align__(16) float s_part[8 * 1024];// 32 KB wave partials (ae|px)
  __shared__ float s_ae[512], s_px[512];          //  4 KB
  __shared__ float s_emb[256];                    //  1 KB
  __shared__ float s_op[8 * 64];                  //  2 KB

  s_qc[t] = qc_ws[i * 1024 + t];
  s_qc[t + 512] = qc_ws[i * 1024 + 512 + t];
  __syncthreads();

  const int c4 = t & 15;       // c-quad
  const int strip = t >> 4;    // 0..31, 16 j each
  const float4* e4 = (const float4*)(e + (size_t)i * 512 * 64);  // [j][16]
  const float4* x4 = (const float4*)x;                           // [j][16]

  // hoist this thread's 64 coefficients into registers
  float ce[4][8], cx[4][8];
#pragma unroll
  for (int cc = 0; cc < 4; ++cc) {
    const int cb = (c4 * 4 + cc) * 16;
#pragma unroll
    for (int h = 0; h < 8; ++h) { ce[cc][h] = s_qc[cb + h]; cx[cc][h] = s_qc[cb + 8 + h]; }
  }

  // ---- Phase 1: logits (1-deep software pipeline on the two streams)
  {
    const int j0 = strip * 16;
    float4 E = e4[j0 * 16 + c4];
    float4 X = x4[j0 * 16 + c4];
    for (int jj = 0; jj < 16; ++jj) {
      const int j = j0 + jj;
      float4 En, Xn;
      if (jj < 15) { En = e4[(j + 1) * 16 + c4]; Xn = x4[(j + 1) * 16 + c4]; }
      float acc[8];
#pragma unroll
      for (int h = 0; h < 8; ++h)
        acc[h] = E.x * ce[0][h] + E.y * ce[1][h] + E.z * ce[2][h] + E.w * ce[3][h]
               + X.x * cx[0][h] + X.y * cx[1][h] + X.z * cx[2][h] + X.w * cx[3][h];
      // butterfly-reduce over the 16 c4 lanes
#pragma unroll
      for (int m = 1; m <= 8; m <<= 1) {
#pragma unroll
        for (int h = 0; h < 8; ++h) acc[h] += __shfl_xor(acc[h], m, 64);
      }
      if (c4 == 0) {
#pragma unroll
        for (int h = 0; h < 8; ++h) s_p[h * 512 + j] = acc[h];
      }
      E = En; X = Xn;
    }
  }
  __syncthreads();

  // ---- Phase 2: softmax per head, 64 lanes per head, normalize in place
  {
    const int n = t >> 6, l64 = t & 63;
    float m = -1e30f;
#pragma unroll
    for (int u = 0; u < 8; ++u) m = fmaxf(m, s_p[n * 512 + l64 + u * 64]);
#pragma unroll
    for (int off = 32; off; off >>= 1) m = fmaxf(m, __shfl_xor(m, off, 64));
    float sum = 0;
#pragma unroll
    for (int u = 0; u < 8; ++u) {
      float p = __expf(s_p[n * 512 + l64 + u * 64] - m);
      s_p[n * 512 + l64 + u * 64] = p;
      sum += p;
    }
#pragma unroll
    for (int off = 32; off; off >>= 1) sum += __shfl_xor(sum, off, 64);
    const float inv = 1.0f / sum;
#pragma unroll
    for (int u = 0; u < 8; ++u) s_p[n * 512 + l64 + u * 64] *= inv;
  }
  __syncthreads();

  // ---- Phase 3: ae[n,c] = sum_j p[n,j]e[j,c];  px[n,c] = sum_j p[n,j]x[j,c]
  {
    float ae[4][8], px[4][8];
#pragma unroll
    for (int cc = 0; cc < 4; ++cc)
#pragma unroll
      for (int h = 0; h < 8; ++h) { ae[cc][h] = 0.f; px[cc][h] = 0.f; }
    const int j0 = strip * 16;
    float4 E = e4[j0 * 16 + c4];
    float4 X = x4[j0 * 16 + c4];
    for (int jj = 0; jj < 16; ++jj) {
      const int j = j0 + jj;
      float4 En, Xn;
      if (jj < 15) { En = e4[(j + 1) * 16 + c4]; Xn = x4[(j + 1) * 16 + c4]; }
      float pr[8];
#pragma unroll
      for (int h = 0; h < 8; ++h) pr[h] = s_p[h * 512 + j];
#pragma unroll
      for (int h = 0; h < 8; ++h) {
        ae[0][h] += pr[h] * E.x; ae[1][h] += pr[h] * E.y;
        ae[2][h] += pr[h] * E.z; ae[3][h] += pr[h] * E.w;
        px[0][h] += pr[h] * X.x; px[1][h] += pr[h] * X.y;
        px[2][h] += pr[h] * X.z; px[3][h] += pr[h] * X.w;
      }
      E = En; X = Xn;
    }
    // reduce the 4 strips within this wave (xor 16, 32)
#pragma unroll
    for (int m = 16; m <= 32; m <<= 1) {
#pragma unroll
      for (int cc = 0; cc < 4; ++cc)
#pragma unroll
        for (int h = 0; h < 8; ++h) {
          ae[cc][h] += __shfl_xor(ae[cc][h], m, 64);
          px[cc][h] += __shfl_xor(px[cc][h], m, 64);
        }
    }
    const int wv = t >> 6;
    if ((t & 48) == 0) {   // lanes 0..15 of each wave
#pragma unroll
      for (int h = 0; h < 8; ++h) {
        *(float4*)&s_part[wv * 1024 + h * 64 + c4 * 4] =
            make_float4(ae[0][h], ae[1][h], ae[2][h], ae[3][h]);
        *(float4*)&s_part[wv * 1024 + 512 + h * 64 + c4 * 4] =
            make_float4(px[0][h], px[1][h], px[2][h], px[3][h]);
      }
    }
  }
  __syncthreads();

  // reduce the 8 wave partials
  {
    float va = 0, vp = 0;
#pragma unroll
    for (int w = 0; w < 8; ++w) {
      va += s_part[w * 1024 + t];
      vp += s_part[w * 1024 + 512 + t];
    }
    s_ae[t] = va; s_px[t] = vp;
  }
  __syncthreads();

  // ---- Epilogue: emb[nd] = sum_c ae[n,c]We[c,nd] + px[n,c]Wv[c,nd]
  {
    const int nd = t & 255, ch = t >> 8, hn = nd >> 5;
    float emb = 0;
    const int cb = ch * 32;
#pragma unroll 8
    for (int c = cb; c < cb + 32; ++c)
      emb += s_ae[hn * 64 + c] * We[c * 256 + nd] + s_px[hn * 64 + c] * Wv[c * 256 + nd];
    s_part[ch * 256 + nd] = emb;
  }
  __syncthreads();
  if (t < 256) s_emb[t] = s_part[t] + s_part[256 + t];
  __syncthreads();
  // out[o] = sum_m emb[m]*Wo[m,o] + bo[o]
  {
    const int o = t & 63, mc = t >> 6;
    float oo = 0;
#pragma unroll 8
    for (int m2 = mc * 32; m2 < mc * 32 + 32; ++m2) oo += s_emb[m2] * Wo[m2 * 64 + o];
    s_op[mc * 64 + o] = oo;
  }
  __syncthreads();
  if (t < 64) {
    float r = bo[t];
#pragma unroll
    for (int w = 0; w < 8; ++w) r += s_op[w * 64 + t];
    out[i * 64 + t] = r;
  }
}

extern "C" void kernel_launch(void* const* d_in, const int* in_sizes, int n_in,
                              void* d_out, int out_size, void* d_ws, size_t ws_size,
                              hipStream_t stream) {
  const float* x  = (const float*)d_in[0];
  const float* e  = (const float*)d_in[1];
  const float* Wq = (const float*)d_in[2];
  const float* Wk = (const float*)d_in[3];
  // Wv = d_in[4] used directly in attn epilogue
  const float* Wv = (const float*)d_in[4];
  const float* We = (const float*)d_in[5];
  const float* Wo = (const float*)d_in[6];
  const float* bo = (const float*)d_in[7];
  float* out = (float*)d_out;

  float* qc_ws = (float*)d_ws;   // 512 x 1024 fp32 = 2 MB

  hipLaunchKernelGGL(coef_kernel, dim3(512), dim3(256), 0, stream,
                     x, Wq, Wk, We, qc_ws);
  hipLaunchKernelGGL(attn_kernel, dim3(512), dim3(512), 0, stream,
                     e, x, qc_ws, We, Wv, Wo, bo, out);
}